// Round 4
// baseline (1120.038 us; speedup 1.0000x reference)
//
#include <hip/hip_runtime.h>
#include <hip/hip_bf16.h>

#define B_ 128
#define N_ 1024
#define E_ 300
#define U_ 128
#define M_ (B_ * N_)   // 131072
#define Z_ (5 * U_)    // 640

typedef __attribute__((ext_vector_type(8))) short bf16x8;
typedef __attribute__((ext_vector_type(4))) float f32x4;
typedef _Float16 h2_t __attribute__((ext_vector_type(2)));
typedef _Float16 f16x4 __attribute__((ext_vector_type(4)));
typedef _Float16 f16x8 __attribute__((ext_vector_type(8)));

__device__ __forceinline__ short f2bf(float f) {
  unsigned u = __builtin_bit_cast(unsigned, f);
  u = (u + 0x7fffu + ((u >> 16) & 1u)) >> 16;
  return (short)u;
}

__device__ __forceinline__ float hsig(float z) {
  float v = __builtin_fmaf(z, 0.2f, 0.5f);
  v = v < 0.f ? 0.f : v;
  v = v > 1.f ? 1.f : v;
  return v;
}

__device__ __forceinline__ float tanh_fast(float x) {
  float p = __expf(2.f * x);
  return 1.f - 2.f * __builtin_amdgcn_rcpf(p + 1.f);
}

// ---------------- Kernel 1: x = relu(state @ Tk) -> H (d_out) and C (ws) ---
__global__ __launch_bounds__(256) void x_gemm(
    const float* __restrict__ A, const float* __restrict__ W,
    float* __restrict__ H, float* __restrict__ C) {
  __shared__ __align__(16) short As[64][40];
  __shared__ __align__(16) short Ws[128][40];
  const int tid = threadIdx.x;
  const int m0 = blockIdx.x * 64;
  f32x4 acc[8] = {};
  const int lane = tid & 63, wv = tid >> 6;
  const int lr = lane & 15, lg = lane >> 4;

  for (int kc = 0; kc < 10; ++kc) {
    const int k0 = kc * 32;
    {
      const int row = tid >> 2, kk = (tid & 3) * 8;
      const float* src = A + (size_t)(m0 + row) * E_ + k0 + kk;
      bf16x8 v;
      if (k0 + 32 <= E_) {
#pragma unroll
        for (int i = 0; i < 8; ++i) v[i] = f2bf(src[i]);
      } else {
#pragma unroll
        for (int i = 0; i < 8; ++i)
          v[i] = (k0 + kk + i < E_) ? f2bf(src[i]) : (short)0;
      }
      *(bf16x8*)&As[row][kk] = v;
    }
#pragma unroll
    for (int s = 0; s < 2; ++s) {
      const int slot = tid + s * 256;
      const int n = slot & 127, kg = slot >> 7;
      bf16x8 v;
      if (k0 + 32 <= E_) {
#pragma unroll
        for (int i = 0; i < 8; ++i) v[i] = f2bf(W[(k0 + kg * 8 + i) * U_ + n]);
      } else {
#pragma unroll
        for (int i = 0; i < 8; ++i) {
          const int k = k0 + kg * 8 + i;
          v[i] = (k < E_) ? f2bf(W[k * U_ + n]) : (short)0;
        }
      }
      *(bf16x8*)&Ws[n][kg * 8] = v;
    }
    __syncthreads();
    bf16x8 a = *(const bf16x8*)&As[wv * 16 + lr][lg * 8];
#pragma unroll
    for (int nt = 0; nt < 8; ++nt) {
      bf16x8 b = *(const bf16x8*)&Ws[nt * 16 + lr][lg * 8];
      acc[nt] = __builtin_amdgcn_mfma_f32_16x16x32_bf16(a, b, acc[nt], 0, 0, 0);
    }
    __syncthreads();
  }
#pragma unroll
  for (int nt = 0; nt < 8; ++nt) {
#pragma unroll
    for (int r = 0; r < 4; ++r) {
      const int m = m0 + wv * 16 + lg * 4 + r;
      const int n = nt * 16 + lr;
      float v = acc[nt][r];
      v = v > 0.f ? v : 0.f;
      H[(size_t)m * U_ + n] = v;
      C[(size_t)m * U_ + n] = v;
    }
  }
}

// ---------------- Kernel 2: xz = x @ K^T + bias (f16 out) ------------------
__global__ __launch_bounds__(256) void xz_gemm(
    const float* __restrict__ X, const float* __restrict__ K,
    const float* __restrict__ bias, _Float16* __restrict__ XZ) {
  __shared__ __align__(16) short As[64][40];
  __shared__ __align__(16) short Ws[128][40];
  const int tid = threadIdx.x;
  const int m0 = blockIdx.x * 64;
  const int n0 = blockIdx.y * 128;
  f32x4 acc[8] = {};
  const int lane = tid & 63, wv = tid >> 6;
  const int lr = lane & 15, lg = lane >> 4;

  for (int kc = 0; kc < 4; ++kc) {
    const int k0 = kc * 32;
    {
      const int row = tid >> 2, kk = (tid & 3) * 8;
      const float* src = X + (size_t)(m0 + row) * U_ + k0 + kk;
      bf16x8 v;
#pragma unroll
      for (int i = 0; i < 8; ++i) v[i] = f2bf(src[i]);
      *(bf16x8*)&As[row][kk] = v;
    }
#pragma unroll
    for (int s = 0; s < 2; ++s) {
      const int slot = tid + s * 256;
      const int n = slot >> 2, kk = (slot & 3) * 8;
      const float* src = K + (size_t)(n0 + n) * U_ + k0 + kk;
      bf16x8 v;
#pragma unroll
      for (int i = 0; i < 8; ++i) v[i] = f2bf(src[i]);
      *(bf16x8*)&Ws[n][kk] = v;
    }
    __syncthreads();
    bf16x8 a = *(const bf16x8*)&As[wv * 16 + lr][lg * 8];
#pragma unroll
    for (int nt = 0; nt < 8; ++nt) {
      bf16x8 b = *(const bf16x8*)&Ws[nt * 16 + lr][lg * 8];
      acc[nt] = __builtin_amdgcn_mfma_f32_16x16x32_bf16(a, b, acc[nt], 0, 0, 0);
    }
    __syncthreads();
  }
#pragma unroll
  for (int nt = 0; nt < 8; ++nt) {
    const int n = n0 + nt * 16 + lr;
    const float bv = bias[n];
#pragma unroll
    for (int r = 0; r < 4; ++r) {
      const int m = m0 + wv * 16 + lg * 4 + r;
      XZ[(size_t)m * Z_ + n] = (_Float16)(acc[nt][r] + bv);
    }
  }
}

// ---------------- Kernel 3: scan, one barrier/step, wave-local gates -------
// 512 threads = 8 waves. Wave w owns z-rows {16w+j, 128+32w+2j, 129+32w+2j,
// 384+16w+j, 512+16w+j : j in [0,16)} as 5 MFMA row-tiles. With the validated
// C/D layout (col=lane&15, row=(lane>>4)*4+reg), lane (col,hi) holds all 5
// z-values for gate u = 16w+4hi+r in acc[0..4][r] -> gates need NO exchange.
__global__ __launch_bounds__(512, 2) void tree_scan4(
    const float* __restrict__ Wr,      // (640,256)
    const int*   __restrict__ child,   // (B,N,2)
    const int*   __restrict__ nv,      // (B,2)
    const _Float16* __restrict__ XZ,   // (B,N,640)
    float* __restrict__ H,             // (B,N,128)
    float* __restrict__ Cst) {         // (B,N,128)
  const int b = blockIdx.x;
  const int tid = threadIdx.x;
  const int lane = tid & 63, w = tid >> 6;
  const int col = lane & 15, hi = lane >> 4;
  int nodes = nv[2 * b];
  int leaves = nv[2 * b + 1];
  if (nodes > N_) nodes = N_;
  if (leaves < 0) leaves = 0;
  float* Hb = H + (size_t)b * N_ * U_;
  float* Cb = Cst + (size_t)b * N_ * U_;
  const int* chb = child + (size_t)b * N_ * 2;
  const _Float16* xzb = XZ + (size_t)b * N_ * Z_;

  // ---- preload R tiles as A-fragments: 5 rt x 8 kt x f16x8 (160 VGPRs) ----
  f16x8 afrag[5][8];
  {
    const int rows[5] = {16 * w + col, 128 + 32 * w + 2 * col,
                         129 + 32 * w + 2 * col, 384 + 16 * w + col,
                         512 + 16 * w + col};
#pragma unroll
    for (int rt = 0; rt < 5; ++rt) {
      const float* rs = Wr + (size_t)rows[rt] * 256 + 8 * hi;
#pragma unroll
      for (int kt = 0; kt < 8; ++kt) {
#pragma unroll
        for (int i = 0; i < 8; ++i)
          afrag[rt][kt][i] = (_Float16)rs[32 * kt + i];
      }
    }
  }

  __shared__ __align__(16) _Float16 hbuf[8][256];  // wave-private h_ch (f16)

  const int u0 = 16 * w + 4 * hi;       // gate base for this lane
  const int mc = 32 * w + 8 * hi;       // c_ch base index (2*u0)

  if (leaves < nodes) {
    // ---- prologue prefetch for t = leaves ----
    int2 cc = *(const int2*)(chb + 2 * leaves);
    f16x4 xzi = *(const f16x4*)(xzb + (size_t)leaves * Z_ + u0);
    f16x8 xzf = *(const f16x8*)(xzb + (size_t)leaves * Z_ + 128 + mc);
    f16x4 xzo = *(const f16x4*)(xzb + (size_t)leaves * Z_ + 384 + u0);
    f16x4 xzg = *(const f16x4*)(xzb + (size_t)leaves * Z_ + 512 + u0);

    for (int t = leaves; t < nodes; ++t) {
      // ---- prefetch t+1 (independent; has the whole step to complete) ----
      const int tn = (t + 1 < nodes) ? t + 1 : t;
      const int2 ccn = *(const int2*)(chb + 2 * tn);
      const f16x4 xzi_n = *(const f16x4*)(xzb + (size_t)tn * Z_ + u0);
      const f16x8 xzf_n = *(const f16x8*)(xzb + (size_t)tn * Z_ + 128 + mc);
      const f16x4 xzo_n = *(const f16x4*)(xzb + (size_t)tn * Z_ + 384 + u0);
      const f16x4 xzg_n = *(const f16x4*)(xzb + (size_t)tn * Z_ + 512 + u0);

      // ---- gather: h_ch slice (1 dwordx4/lane) + c_ch slice (2/lane) ----
      const int m4 = 4 * lane;  // 0..252
      const float4 hv =
          *(const float4*)(Hb + (size_t)(lane < 32 ? cc.x : cc.y) * U_ +
                           (m4 & 127));
      const float* cbase =
          Cb + (size_t)(w < 4 ? cc.x : cc.y) * U_ + (mc & 127);
      const float4 cv0 = *(const float4*)cbase;
      const float4 cv1 = *(const float4*)(cbase + 4);

      // ---- stage h to wave-private LDS (no barrier: same-wave dep) ----
      uint2 hp;
      hp.x = __builtin_bit_cast(unsigned, __builtin_amdgcn_cvt_pkrtz(hv.x, hv.y));
      hp.y = __builtin_bit_cast(unsigned, __builtin_amdgcn_cvt_pkrtz(hv.z, hv.w));
      *(uint2*)&hbuf[w][m4] = hp;

      // ---- B fragments (broadcast columns) ----
      f16x8 bfrag[8];
#pragma unroll
      for (int kt = 0; kt < 8; ++kt)
        bfrag[kt] = *(const f16x8*)&hbuf[w][32 * kt + 8 * hi];

      // ---- MFMA: 5 tiles x 8 k-steps ----
      f32x4 acc[5] = {};
#pragma unroll
      for (int kt = 0; kt < 8; ++kt) {
#pragma unroll
        for (int rt = 0; rt < 5; ++rt)
          acc[rt] = __builtin_amdgcn_mfma_f32_16x16x32_f16(
              afrag[rt][kt], bfrag[kt], acc[rt], 0, 0, 0);
      }

      // ---- gates (every lane computes its u0..u0+3; col 0 stores) ----
      const float ce[8] = {cv0.x, cv0.y, cv0.z, cv0.w,
                           cv1.x, cv1.y, cv1.z, cv1.w};
      f32x4 hn4, cn4;
#pragma unroll
      for (int r = 0; r < 4; ++r) {
        const float zi = acc[0][r] + (float)xzi[r];
        const float zf0 = acc[1][r] + (float)xzf[2 * r];
        const float zf1 = acc[2][r] + (float)xzf[2 * r + 1];
        const float zo = acc[3][r] + (float)xzo[r];
        const float zg = acc[4][r] + (float)xzg[r];
        const float cn = ce[2 * r] * hsig(zf0) + ce[2 * r + 1] * hsig(zf1) +
                         hsig(zi) * tanh_fast(zg);
        cn4[r] = cn;
        hn4[r] = hsig(zo) * tanh_fast(cn);
      }
      if (col == 0) {
        *(f32x4*)(Hb + (size_t)t * U_ + u0) = hn4;
        *(f32x4*)(Cb + (size_t)t * U_ + u0) = cn4;
      }

      // ---- single barrier: stores visible before next gather ----
      __syncthreads();

      cc = ccn;
      xzi = xzi_n;
      xzf = xzf_n;
      xzo = xzo_n;
      xzg = xzg_n;
    }
  }

  // zero rows t >= num_nodes
  const int total = (N_ - nodes) * U_;
  for (int idx = tid; idx < total; idx += 512)
    Hb[(size_t)nodes * U_ + idx] = 0.f;
}

// ---------------- Fallback scan (R1 version, known-correct) ----------------
__global__ __launch_bounds__(640, 1) void tree_scan_fb(
    const float* __restrict__ Wk, const float* __restrict__ Wr,
    const float* __restrict__ bias, const int* __restrict__ child,
    const int* __restrict__ nv, float* __restrict__ H,
    float* __restrict__ Cst) {
  const int b = blockIdx.x;
  const int tid = threadIdx.x;
  int nodes = nv[2 * b];
  int leaves = nv[2 * b + 1];
  if (nodes > N_) nodes = N_;
  if (leaves < 0) leaves = 0;
  float* Hb = H + (size_t)b * N_ * U_;
  float* Cb = Cst + (size_t)b * N_ * U_;
  const int* chb = child + (size_t)b * N_ * 2;

  unsigned wreg[192];
  {
    const float* kr = Wk + tid * U_;
#pragma unroll
    for (int i = 0; i < 64; ++i)
      wreg[i] = __builtin_bit_cast(
          unsigned, __builtin_amdgcn_cvt_pkrtz(kr[2 * i], kr[2 * i + 1]));
    const float* rr = Wr + tid * 2 * U_;
#pragma unroll
    for (int i = 0; i < 128; ++i)
      wreg[64 + i] = __builtin_bit_cast(
          unsigned, __builtin_amdgcn_cvt_pkrtz(rr[2 * i], rr[2 * i + 1]));
  }
  const float bj = bias[tid];

  __shared__ __align__(16) unsigned act2[192];
  __shared__ float zbuf[640];
  __shared__ float2 cbuf[128];

  for (int t = leaves; t < nodes; ++t) {
    if (tid < 192) {
      float2 v;
      if (tid < 64) {
        v = *(const float2*)(Hb + t * U_ + 2 * tid);
      } else {
        const int m = 2 * tid - 128;
        const int cc = chb[t * 2 + (m >> 7)];
        v = *(const float2*)(Hb + cc * U_ + (m & 127));
      }
      act2[tid] =
          __builtin_bit_cast(unsigned, __builtin_amdgcn_cvt_pkrtz(v.x, v.y));
    } else if (tid < 320) {
      const int u = tid - 192;
      const int m = 2 * u;
      const int cc = chb[t * 2 + (m >> 7)];
      cbuf[u] = *(const float2*)(Cb + cc * U_ + (m & 127));
    }
    __syncthreads();

    float acc = bj;
    {
      const uint4* a4 = (const uint4*)act2;
#pragma unroll
      for (int q = 0; q < 48; ++q) {
        const uint4 v = a4[q];
        acc = __builtin_amdgcn_fdot2(__builtin_bit_cast(h2_t, wreg[4 * q + 0]),
                                     __builtin_bit_cast(h2_t, v.x), acc, false);
        acc = __builtin_amdgcn_fdot2(__builtin_bit_cast(h2_t, wreg[4 * q + 1]),
                                     __builtin_bit_cast(h2_t, v.y), acc, false);
        acc = __builtin_amdgcn_fdot2(__builtin_bit_cast(h2_t, wreg[4 * q + 2]),
                                     __builtin_bit_cast(h2_t, v.z), acc, false);
        acc = __builtin_amdgcn_fdot2(__builtin_bit_cast(h2_t, wreg[4 * q + 3]),
                                     __builtin_bit_cast(h2_t, v.w), acc, false);
      }
    }
    zbuf[tid] = acc;
    __syncthreads();

    if (tid < U_) {
      const float zi = zbuf[tid];
      const float zf0 = zbuf[U_ + 2 * tid];
      const float zf1 = zbuf[U_ + 2 * tid + 1];
      const float zo = zbuf[3 * U_ + tid];
      const float zg = zbuf[4 * U_ + tid];
      const float2 cc = cbuf[tid];
      const float ig = hsig(zi);
      const float f0 = hsig(zf0);
      const float f1 = hsig(zf1);
      const float og = hsig(zo);
      const float gg = tanh_fast(zg);
      const float cn = cc.x * f0 + cc.y * f1 + ig * gg;
      const float hn = og * tanh_fast(cn);
      Hb[t * U_ + tid] = hn;
      Cb[t * U_ + tid] = cn;
    }
    __syncthreads();
  }

  const int total = (N_ - nodes) * U_;
  for (int idx = tid; idx < total; idx += 640)
    Hb[nodes * U_ + idx] = 0.f;
}

extern "C" void kernel_launch(void* const* d_in, const int* in_sizes, int n_in,
                              void* d_out, int out_size, void* d_ws,
                              size_t ws_size, hipStream_t stream) {
  const float* state = (const float*)d_in[0];
  const float* tk    = (const float*)d_in[1];
  const float* Wk    = (const float*)d_in[2];
  const float* Wr    = (const float*)d_in[3];
  const float* bias  = (const float*)d_in[4];
  const int*   child = (const int*)d_in[5];
  const int*   nvp   = (const int*)d_in[6];
  float* H = (float*)d_out;

  const size_t c_bytes = (size_t)M_ * U_ * sizeof(float);      // 64 MiB
  const size_t xz_bytes = (size_t)M_ * Z_ * sizeof(_Float16);  // 160 MiB
  float* C = (float*)d_ws;

  x_gemm<<<M_ / 64, 256, 0, stream>>>(state, tk, H, C);

  if (ws_size >= c_bytes + xz_bytes) {
    _Float16* XZ = (_Float16*)((char*)d_ws + c_bytes);
    xz_gemm<<<dim3(M_ / 64, 5), 256, 0, stream>>>(H, Wk, bias, XZ);
    tree_scan4<<<B_, 512, 0, stream>>>(Wr, child, nvp, XZ, H, C);
  } else {
    tree_scan_fb<<<B_, 640, 0, stream>>>(Wk, Wr, bias, child, nvp, H, C);
  }
}

// Round 5
// 1100.490 us; speedup vs baseline: 1.0178x; 1.0178x over previous
//
#include <hip/hip_runtime.h>
#include <hip/hip_bf16.h>

#define B_ 128
#define N_ 1024
#define E_ 300
#define U_ 128
#define M_ (B_ * N_)   // 131072
#define Z_ (5 * U_)    // 640

typedef __attribute__((ext_vector_type(8))) short bf16x8;
typedef __attribute__((ext_vector_type(4))) float f32x4;
typedef _Float16 h2_t __attribute__((ext_vector_type(2)));
typedef _Float16 f16x4 __attribute__((ext_vector_type(4)));
typedef _Float16 f16x8 __attribute__((ext_vector_type(8)));

__device__ __forceinline__ short f2bf(float f) {
  unsigned u = __builtin_bit_cast(unsigned, f);
  u = (u + 0x7fffu + ((u >> 16) & 1u)) >> 16;
  return (short)u;
}

__device__ __forceinline__ float hsig(float z) {
  float v = __builtin_fmaf(z, 0.2f, 0.5f);
  v = v < 0.f ? 0.f : v;
  v = v > 1.f ? 1.f : v;
  return v;
}

__device__ __forceinline__ float tanh_fast(float x) {
  float p = __expf(2.f * x);
  return 1.f - 2.f * __builtin_amdgcn_rcpf(p + 1.f);
}

// ---------------- Kernel 1: x = relu(state @ Tk) -> H (d_out) and C (ws) ---
__global__ __launch_bounds__(256) void x_gemm(
    const float* __restrict__ A, const float* __restrict__ W,
    float* __restrict__ H, float* __restrict__ C) {
  __shared__ __align__(16) short As[64][40];
  __shared__ __align__(16) short Ws[128][40];
  const int tid = threadIdx.x;
  const int m0 = blockIdx.x * 64;
  f32x4 acc[8] = {};
  const int lane = tid & 63, wv = tid >> 6;
  const int lr = lane & 15, lg = lane >> 4;

  for (int kc = 0; kc < 10; ++kc) {
    const int k0 = kc * 32;
    {
      const int row = tid >> 2, kk = (tid & 3) * 8;
      const float* src = A + (size_t)(m0 + row) * E_ + k0 + kk;
      bf16x8 v;
      if (k0 + 32 <= E_) {
#pragma unroll
        for (int i = 0; i < 8; ++i) v[i] = f2bf(src[i]);
      } else {
#pragma unroll
        for (int i = 0; i < 8; ++i)
          v[i] = (k0 + kk + i < E_) ? f2bf(src[i]) : (short)0;
      }
      *(bf16x8*)&As[row][kk] = v;
    }
#pragma unroll
    for (int s = 0; s < 2; ++s) {
      const int slot = tid + s * 256;
      const int n = slot & 127, kg = slot >> 7;
      bf16x8 v;
      if (k0 + 32 <= E_) {
#pragma unroll
        for (int i = 0; i < 8; ++i) v[i] = f2bf(W[(k0 + kg * 8 + i) * U_ + n]);
      } else {
#pragma unroll
        for (int i = 0; i < 8; ++i) {
          const int k = k0 + kg * 8 + i;
          v[i] = (k < E_) ? f2bf(W[k * U_ + n]) : (short)0;
        }
      }
      *(bf16x8*)&Ws[n][kg * 8] = v;
    }
    __syncthreads();
    bf16x8 a = *(const bf16x8*)&As[wv * 16 + lr][lg * 8];
#pragma unroll
    for (int nt = 0; nt < 8; ++nt) {
      bf16x8 b = *(const bf16x8*)&Ws[nt * 16 + lr][lg * 8];
      acc[nt] = __builtin_amdgcn_mfma_f32_16x16x32_bf16(a, b, acc[nt], 0, 0, 0);
    }
    __syncthreads();
  }
#pragma unroll
  for (int nt = 0; nt < 8; ++nt) {
#pragma unroll
    for (int r = 0; r < 4; ++r) {
      const int m = m0 + wv * 16 + lg * 4 + r;
      const int n = nt * 16 + lr;
      float v = acc[nt][r];
      v = v > 0.f ? v : 0.f;
      H[(size_t)m * U_ + n] = v;
      C[(size_t)m * U_ + n] = v;
    }
  }
}

// ---------------- Kernel 2: xz = x @ K^T + bias (f16 out) ------------------
// Skips blocks whose t-range is entirely outside [leaves, nodes) for their
// batch (tree_scan never reads those XZ rows) -> halves XZ traffic here.
__global__ __launch_bounds__(256) void xz_gemm(
    const float* __restrict__ X, const float* __restrict__ K,
    const float* __restrict__ bias, const int* __restrict__ nv,
    _Float16* __restrict__ XZ) {
  const int m0 = blockIdx.x * 64;
  {
    const int bb = m0 >> 10;           // batch of this row-block (N_=1024)
    const int t0 = m0 & (N_ - 1);
    const int nodes = nv[2 * bb], leaves = nv[2 * bb + 1];
    if (t0 + 64 <= leaves || t0 >= nodes) return;
  }
  __shared__ __align__(16) short As[64][40];
  __shared__ __align__(16) short Ws[128][40];
  const int tid = threadIdx.x;
  const int n0 = blockIdx.y * 128;
  f32x4 acc[8] = {};
  const int lane = tid & 63, wv = tid >> 6;
  const int lr = lane & 15, lg = lane >> 4;

  for (int kc = 0; kc < 4; ++kc) {
    const int k0 = kc * 32;
    {
      const int row = tid >> 2, kk = (tid & 3) * 8;
      const float* src = X + (size_t)(m0 + row) * U_ + k0 + kk;
      bf16x8 v;
#pragma unroll
      for (int i = 0; i < 8; ++i) v[i] = f2bf(src[i]);
      *(bf16x8*)&As[row][kk] = v;
    }
#pragma unroll
    for (int s = 0; s < 2; ++s) {
      const int slot = tid + s * 256;
      const int n = slot >> 2, kk = (slot & 3) * 8;
      const float* src = K + (size_t)(n0 + n) * U_ + k0 + kk;
      bf16x8 v;
#pragma unroll
      for (int i = 0; i < 8; ++i) v[i] = f2bf(src[i]);
      *(bf16x8*)&Ws[n][kk] = v;
    }
    __syncthreads();
    bf16x8 a = *(const bf16x8*)&As[wv * 16 + lr][lg * 8];
#pragma unroll
    for (int nt = 0; nt < 8; ++nt) {
      bf16x8 b = *(const bf16x8*)&Ws[nt * 16 + lr][lg * 8];
      acc[nt] = __builtin_amdgcn_mfma_f32_16x16x32_bf16(a, b, acc[nt], 0, 0, 0);
    }
    __syncthreads();
  }
#pragma unroll
  for (int nt = 0; nt < 8; ++nt) {
    const int n = n0 + nt * 16 + lr;
    const float bv = bias[n];
#pragma unroll
    for (int r = 0; r < 4; ++r) {
      const int m = m0 + wv * 16 + lg * 4 + r;
      XZ[(size_t)m * Z_ + n] = (_Float16)(acc[nt][r] + bv);
    }
  }
}

// ---------------- Kernel 3: scan, gather-first / prefetch-second -----------
// 512 threads = 8 waves; wave-local gates (see R4 comment). KEY FIX vs R4:
// vmcnt retires IN ISSUE ORDER, so the h/c gather must be issued BEFORE the
// t+1 prefetch, else consuming the gather drains the HBM-latency prefetch.
// sched_barrier(0) fences keep LLVM from re-hoisting the prefetch.
__global__ __launch_bounds__(512, 2) void tree_scan4(
    const float* __restrict__ Wr,      // (640,256)
    const int*   __restrict__ child,   // (B,N,2)
    const int*   __restrict__ nv,      // (B,2)
    const _Float16* __restrict__ XZ,   // (B,N,640)
    float* __restrict__ H,             // (B,N,128)
    float* __restrict__ Cst) {         // (B,N,128)
  const int b = blockIdx.x;
  const int tid = threadIdx.x;
  const int lane = tid & 63, w = tid >> 6;
  const int col = lane & 15, hi = lane >> 4;
  int nodes = nv[2 * b];
  int leaves = nv[2 * b + 1];
  if (nodes > N_) nodes = N_;
  if (leaves < 0) leaves = 0;
  float* Hb = H + (size_t)b * N_ * U_;
  float* Cb = Cst + (size_t)b * N_ * U_;
  const int* chb = child + (size_t)b * N_ * 2;
  const _Float16* xzb = XZ + (size_t)b * N_ * Z_;

  // ---- preload R tiles as A-fragments: 5 rt x 8 kt x f16x8 (160 VGPRs) ----
  f16x8 afrag[5][8];
  {
    const int rows[5] = {16 * w + col, 128 + 32 * w + 2 * col,
                         129 + 32 * w + 2 * col, 384 + 16 * w + col,
                         512 + 16 * w + col};
#pragma unroll
    for (int rt = 0; rt < 5; ++rt) {
      const float* rs = Wr + (size_t)rows[rt] * 256 + 8 * hi;
#pragma unroll
      for (int kt = 0; kt < 8; ++kt) {
#pragma unroll
        for (int i = 0; i < 8; ++i)
          afrag[rt][kt][i] = (_Float16)rs[32 * kt + i];
      }
    }
  }

  __shared__ __align__(16) _Float16 hbuf[8][256];  // wave-private h_ch (f16)

  const int u0 = 16 * w + 4 * hi;       // gate base for this lane
  const int mc = 32 * w + 8 * hi;       // c_ch base index (2*u0)

  if (leaves < nodes) {
    // ---- prologue prefetch for t = leaves ----
    int2 cc = *(const int2*)(chb + 2 * leaves);
    f16x4 xzi = *(const f16x4*)(xzb + (size_t)leaves * Z_ + u0);
    f16x8 xzf = *(const f16x8*)(xzb + (size_t)leaves * Z_ + 128 + mc);
    f16x4 xzo = *(const f16x4*)(xzb + (size_t)leaves * Z_ + 384 + u0);
    f16x4 xzg = *(const f16x4*)(xzb + (size_t)leaves * Z_ + 512 + u0);

    for (int t = leaves; t < nodes; ++t) {
      // ---- (1) gather FIRST: h_ch (1 dwordx4/lane) + c_ch (2/lane) ----
      const int m4 = 4 * lane;  // 0..252
      const float4 hv =
          *(const float4*)(Hb + (size_t)(lane < 32 ? cc.x : cc.y) * U_ +
                           (m4 & 127));
      const float* cbase =
          Cb + (size_t)(w < 4 ? cc.x : cc.y) * U_ + (mc & 127);
      const float4 cv0 = *(const float4*)cbase;
      const float4 cv1 = *(const float4*)(cbase + 4);
      __builtin_amdgcn_sched_barrier(0);

      // ---- (2) prefetch t+1 (stays outstanding past gather-consume) ----
      const int tn = (t + 1 < nodes) ? t + 1 : t;
      const int2 ccn = *(const int2*)(chb + 2 * tn);
      const f16x4 xzi_n = *(const f16x4*)(xzb + (size_t)tn * Z_ + u0);
      const f16x8 xzf_n = *(const f16x8*)(xzb + (size_t)tn * Z_ + 128 + mc);
      const f16x4 xzo_n = *(const f16x4*)(xzb + (size_t)tn * Z_ + 384 + u0);
      const f16x4 xzg_n = *(const f16x4*)(xzb + (size_t)tn * Z_ + 512 + u0);
      __builtin_amdgcn_sched_barrier(0);

      // ---- (3) stage h to wave-private LDS (same-wave dep, no barrier) ----
      uint2 hp;
      hp.x = __builtin_bit_cast(unsigned, __builtin_amdgcn_cvt_pkrtz(hv.x, hv.y));
      hp.y = __builtin_bit_cast(unsigned, __builtin_amdgcn_cvt_pkrtz(hv.z, hv.w));
      *(uint2*)&hbuf[w][m4] = hp;

      // ---- B fragments (broadcast columns) ----
      f16x8 bfrag[8];
#pragma unroll
      for (int kt = 0; kt < 8; ++kt)
        bfrag[kt] = *(const f16x8*)&hbuf[w][32 * kt + 8 * hi];

      // ---- MFMA: 5 tiles x 8 k-steps ----
      f32x4 acc[5] = {};
#pragma unroll
      for (int kt = 0; kt < 8; ++kt) {
#pragma unroll
        for (int rt = 0; rt < 5; ++rt)
          acc[rt] = __builtin_amdgcn_mfma_f32_16x16x32_f16(
              afrag[rt][kt], bfrag[kt], acc[rt], 0, 0, 0);
      }

      // ---- gates (every lane computes its u0..u0+3; col 0 stores) ----
      const float ce[8] = {cv0.x, cv0.y, cv0.z, cv0.w,
                           cv1.x, cv1.y, cv1.z, cv1.w};
      f32x4 hn4, cn4;
#pragma unroll
      for (int r = 0; r < 4; ++r) {
        const float zi = acc[0][r] + (float)xzi[r];
        const float zf0 = acc[1][r] + (float)xzf[2 * r];
        const float zf1 = acc[2][r] + (float)xzf[2 * r + 1];
        const float zo = acc[3][r] + (float)xzo[r];
        const float zg = acc[4][r] + (float)xzg[r];
        const float cn = ce[2 * r] * hsig(zf0) + ce[2 * r + 1] * hsig(zf1) +
                         hsig(zi) * tanh_fast(zg);
        cn4[r] = cn;
        hn4[r] = hsig(zo) * tanh_fast(cn);
      }
      if (col == 0) {
        *(f32x4*)(Hb + (size_t)t * U_ + u0) = hn4;
        *(f32x4*)(Cb + (size_t)t * U_ + u0) = cn4;
      }

      // ---- single barrier: stores visible before next gather ----
      __syncthreads();

      cc = ccn;
      xzi = xzi_n;
      xzf = xzf_n;
      xzo = xzo_n;
      xzg = xzg_n;
    }
  }

  // zero rows t >= num_nodes
  const int total = (N_ - nodes) * U_;
  for (int idx = tid; idx < total; idx += 512)
    Hb[(size_t)nodes * U_ + idx] = 0.f;
}

extern "C" void kernel_launch(void* const* d_in, const int* in_sizes, int n_in,
                              void* d_out, int out_size, void* d_ws,
                              size_t ws_size, hipStream_t stream) {
  const float* state = (const float*)d_in[0];
  const float* tk    = (const float*)d_in[1];
  const float* Wk    = (const float*)d_in[2];
  const float* Wr    = (const float*)d_in[3];
  const float* bias  = (const float*)d_in[4];
  const int*   child = (const int*)d_in[5];
  const int*   nvp   = (const int*)d_in[6];
  float* H = (float*)d_out;

  const size_t c_bytes = (size_t)M_ * U_ * sizeof(float);      // 64 MiB
  float* C = (float*)d_ws;
  _Float16* XZ = (_Float16*)((char*)d_ws + c_bytes);

  x_gemm<<<M_ / 64, 256, 0, stream>>>(state, tk, H, C);
  xz_gemm<<<dim3(M_ / 64, 5), 256, 0, stream>>>(H, Wk, bias, nvp, XZ);
  tree_scan4<<<B_, 512, 0, stream>>>(Wr, child, nvp, XZ, H, C);
}

// Round 6
// 1053.967 us; speedup vs baseline: 1.0627x; 1.0441x over previous
//
#include <hip/hip_runtime.h>
#include <hip/hip_bf16.h>

#define B_ 128
#define N_ 1024
#define E_ 300
#define U_ 128
#define M_ (B_ * N_)   // 131072
#define Z_ (5 * U_)    // 640

typedef __attribute__((ext_vector_type(8))) short bf16x8;
typedef __attribute__((ext_vector_type(4))) float f32x4;
typedef _Float16 h2_t __attribute__((ext_vector_type(2)));
typedef _Float16 f16x4 __attribute__((ext_vector_type(4)));
typedef _Float16 f16x8 __attribute__((ext_vector_type(8)));

__device__ __forceinline__ short f2bf(float f) {
  unsigned u = __builtin_bit_cast(unsigned, f);
  u = (u + 0x7fffu + ((u >> 16) & 1u)) >> 16;
  return (short)u;
}

__device__ __forceinline__ float hsig(float z) {
  float v = __builtin_fmaf(z, 0.2f, 0.5f);
  v = v < 0.f ? 0.f : v;
  v = v > 1.f ? 1.f : v;
  return v;
}

__device__ __forceinline__ float tanh_fast(float x) {
  float p = __expf(2.f * x);
  return 1.f - 2.f * __builtin_amdgcn_rcpf(p + 1.f);
}

// ---------------- Kernel 1: x = relu(state @ Tk) -> H (d_out) and C (ws) ---
__global__ __launch_bounds__(256) void x_gemm(
    const float* __restrict__ A, const float* __restrict__ W,
    float* __restrict__ H, float* __restrict__ C) {
  __shared__ __align__(16) short As[64][40];
  __shared__ __align__(16) short Ws[128][40];
  const int tid = threadIdx.x;
  const int m0 = blockIdx.x * 64;
  f32x4 acc[8] = {};
  const int lane = tid & 63, wv = tid >> 6;
  const int lr = lane & 15, lg = lane >> 4;

  for (int kc = 0; kc < 10; ++kc) {
    const int k0 = kc * 32;
    {
      const int row = tid >> 2, kk = (tid & 3) * 8;
      const float* src = A + (size_t)(m0 + row) * E_ + k0 + kk;
      bf16x8 v;
      if (k0 + 32 <= E_) {
#pragma unroll
        for (int i = 0; i < 8; ++i) v[i] = f2bf(src[i]);
      } else {
#pragma unroll
        for (int i = 0; i < 8; ++i)
          v[i] = (k0 + kk + i < E_) ? f2bf(src[i]) : (short)0;
      }
      *(bf16x8*)&As[row][kk] = v;
    }
#pragma unroll
    for (int s = 0; s < 2; ++s) {
      const int slot = tid + s * 256;
      const int n = slot & 127, kg = slot >> 7;
      bf16x8 v;
      if (k0 + 32 <= E_) {
#pragma unroll
        for (int i = 0; i < 8; ++i) v[i] = f2bf(W[(k0 + kg * 8 + i) * U_ + n]);
      } else {
#pragma unroll
        for (int i = 0; i < 8; ++i) {
          const int k = k0 + kg * 8 + i;
          v[i] = (k < E_) ? f2bf(W[k * U_ + n]) : (short)0;
        }
      }
      *(bf16x8*)&Ws[n][kg * 8] = v;
    }
    __syncthreads();
    bf16x8 a = *(const bf16x8*)&As[wv * 16 + lr][lg * 8];
#pragma unroll
    for (int nt = 0; nt < 8; ++nt) {
      bf16x8 b = *(const bf16x8*)&Ws[nt * 16 + lr][lg * 8];
      acc[nt] = __builtin_amdgcn_mfma_f32_16x16x32_bf16(a, b, acc[nt], 0, 0, 0);
    }
    __syncthreads();
  }
#pragma unroll
  for (int nt = 0; nt < 8; ++nt) {
#pragma unroll
    for (int r = 0; r < 4; ++r) {
      const int m = m0 + wv * 16 + lg * 4 + r;
      const int n = nt * 16 + lr;
      float v = acc[nt][r];
      v = v > 0.f ? v : 0.f;
      H[(size_t)m * U_ + n] = v;
      C[(size_t)m * U_ + n] = v;
    }
  }
}

// ---------------- Kernel 2: xz = x @ K^T + bias (f16 out) ------------------
__global__ __launch_bounds__(256) void xz_gemm(
    const float* __restrict__ X, const float* __restrict__ K,
    const float* __restrict__ bias, const int* __restrict__ nv,
    _Float16* __restrict__ XZ) {
  const int m0 = blockIdx.x * 64;
  {
    const int bb = m0 >> 10;
    const int t0 = m0 & (N_ - 1);
    const int nodes = nv[2 * bb], leaves = nv[2 * bb + 1];
    if (t0 + 64 <= leaves || t0 >= nodes) return;
  }
  __shared__ __align__(16) short As[64][40];
  __shared__ __align__(16) short Ws[128][40];
  const int tid = threadIdx.x;
  const int n0 = blockIdx.y * 128;
  f32x4 acc[8] = {};
  const int lane = tid & 63, wv = tid >> 6;
  const int lr = lane & 15, lg = lane >> 4;

  for (int kc = 0; kc < 4; ++kc) {
    const int k0 = kc * 32;
    {
      const int row = tid >> 2, kk = (tid & 3) * 8;
      const float* src = X + (size_t)(m0 + row) * U_ + k0 + kk;
      bf16x8 v;
#pragma unroll
      for (int i = 0; i < 8; ++i) v[i] = f2bf(src[i]);
      *(bf16x8*)&As[row][kk] = v;
    }
#pragma unroll
    for (int s = 0; s < 2; ++s) {
      const int slot = tid + s * 256;
      const int n = slot >> 2, kk = (slot & 3) * 8;
      const float* src = K + (size_t)(n0 + n) * U_ + k0 + kk;
      bf16x8 v;
#pragma unroll
      for (int i = 0; i < 8; ++i) v[i] = f2bf(src[i]);
      *(bf16x8*)&Ws[n][kk] = v;
    }
    __syncthreads();
    bf16x8 a = *(const bf16x8*)&As[wv * 16 + lr][lg * 8];
#pragma unroll
    for (int nt = 0; nt < 8; ++nt) {
      bf16x8 b = *(const bf16x8*)&Ws[nt * 16 + lr][lg * 8];
      acc[nt] = __builtin_amdgcn_mfma_f32_16x16x32_bf16(a, b, acc[nt], 0, 0, 0);
    }
    __syncthreads();
  }
#pragma unroll
  for (int nt = 0; nt < 8; ++nt) {
    const int n = n0 + nt * 16 + lr;
    const float bv = bias[n];
#pragma unroll
    for (int r = 0; r < 4; ++r) {
      const int m = m0 + wv * 16 + lg * 4 + r;
      XZ[(size_t)m * Z_ + n] = (_Float16)(acc[nt][r] + bv);
    }
  }
}

// ---------------- Kernel 3: scan with CROSS-STEP gather pipelining ---------
// 512 threads = 8 waves; wave-local gates (validated R4 layout). The gather
// for step t+1 (children = static indices) is ISSUED DURING step t and
// overlaps its compute; the rare hazard child==t (just-computed row, ~0.2%/
// step) is patched at the top of step t+1 by reloading that row (L2-hot).
// XZ rows live in double-buffered LDS (staged a step ahead) to cut VGPRs.
__global__ __launch_bounds__(512, 2) void tree_scan5(
    const float* __restrict__ Wr,      // (640,256)
    const int*   __restrict__ child,   // (B,N,2)
    const int*   __restrict__ nv,      // (B,2)
    const _Float16* __restrict__ XZ,   // (B,N,640)
    float* __restrict__ H,             // (B,N,128)
    float* __restrict__ Cst) {         // (B,N,128)
  const int b = blockIdx.x;
  const int tid = threadIdx.x;
  const int lane = tid & 63, w = tid >> 6;
  const int col = lane & 15, hi = lane >> 4;
  int nodes = nv[2 * b];
  int leaves = nv[2 * b + 1];
  if (nodes > N_) nodes = N_;
  if (leaves < 0) leaves = 0;
  float* Hb = H + (size_t)b * N_ * U_;
  float* Cb = Cst + (size_t)b * N_ * U_;
  const int* chb = child + (size_t)b * N_ * 2;
  const _Float16* xzb = XZ + (size_t)b * N_ * Z_;

  // ---- preload R tiles as A-fragments: 5 rt x 8 kt x f16x8 ----
  f16x8 afrag[5][8];
  {
    const int rows[5] = {16 * w + col, 128 + 32 * w + 2 * col,
                         129 + 32 * w + 2 * col, 384 + 16 * w + col,
                         512 + 16 * w + col};
#pragma unroll
    for (int rt = 0; rt < 5; ++rt) {
      const float* rs = Wr + (size_t)rows[rt] * 256 + 8 * hi;
#pragma unroll
      for (int kt = 0; kt < 8; ++kt) {
#pragma unroll
        for (int i = 0; i < 8; ++i)
          afrag[rt][kt][i] = (_Float16)rs[32 * kt + i];
      }
    }
  }

  __shared__ __align__(16) _Float16 hbuf[8][256];   // wave-private h_ch (4KB)
  __shared__ __align__(16) _Float16 xzs[2][Z_];     // double-buffered xz row

  const int u0 = 16 * w + 4 * hi;   // gate base for this lane
  const int mc = 2 * u0;            // c_ch base index
  const int m4 = 4 * lane;          // h gather offset

  if (leaves < nodes) {
    // ---- prologue: gather for t0, xz(t0) -> xzs[0] ----
    int2 ccT = *(const int2*)(chb + 2 * leaves);
    float4 hv = *(const float4*)(Hb + (size_t)(lane < 32 ? ccT.x : ccT.y) * U_ +
                                 (m4 & 127));
    const float* cbp = Cb + (size_t)(w < 4 ? ccT.x : ccT.y) * U_ + (mc & 127);
    float4 cv0 = ((const float4*)cbp)[0];
    float4 cv1 = ((const float4*)cbp)[1];
    if (tid < 160)
      *(f16x4*)&xzs[0][4 * tid] =
          *(const f16x4*)(xzb + (size_t)leaves * Z_ + 4 * tid);
    const int tn1 = (leaves + 1 < nodes) ? leaves + 1 : leaves;
    int2 ccN = *(const int2*)(chb + 2 * tn1);
    __syncthreads();

    int cbuf = 0;
    for (int t = leaves; t < nodes; ++t) {
      const int tn = (t + 1 < nodes) ? t + 1 : t;

      // ---- A. patch stale gather (child row == t-1, computed last step) --
      if (t > leaves) {
        if (ccT.x == t - 1 && lane < 32)
          hv = *(const float4*)(Hb + (size_t)(t - 1) * U_ + m4);
        if (ccT.y == t - 1 && lane >= 32)
          hv = *(const float4*)(Hb + (size_t)(t - 1) * U_ + (m4 & 127));
        const int crow = (w < 4) ? ccT.x : ccT.y;
        if (crow == t - 1) {
          const float* cpp = Cb + (size_t)(t - 1) * U_ + (mc & 127);
          cv0 = ((const float4*)cpp)[0];
          cv1 = ((const float4*)cpp)[1];
        }
      }

      // ---- B. stage h -> wave-private LDS; read xz gates early ----
      uint2 hp;
      hp.x = __builtin_bit_cast(unsigned, __builtin_amdgcn_cvt_pkrtz(hv.x, hv.y));
      hp.y = __builtin_bit_cast(unsigned, __builtin_amdgcn_cvt_pkrtz(hv.z, hv.w));
      *(uint2*)&hbuf[w][m4] = hp;
      const f16x4 xzi = *(const f16x4*)&xzs[cbuf][u0];
      const f16x8 xzf = *(const f16x8*)&xzs[cbuf][128 + mc];
      const f16x4 xzo = *(const f16x4*)&xzs[cbuf][384 + u0];
      const f16x4 xzg = *(const f16x4*)&xzs[cbuf][512 + u0];

      // ---- C. issue NEXT gather (children of t+1) + xz(t+1) + child(t+2) --
      float4 hv_n = *(const float4*)(
          Hb + (size_t)(lane < 32 ? ccN.x : ccN.y) * U_ + (m4 & 127));
      const float* cbn = Cb + (size_t)(w < 4 ? ccN.x : ccN.y) * U_ + (mc & 127);
      const float4 cv0n = ((const float4*)cbn)[0];
      const float4 cv1n = ((const float4*)cbn)[1];
      f16x4 xztmp = {};
      if (tid < 160)
        xztmp = *(const f16x4*)(xzb + (size_t)tn * Z_ + 4 * tid);
      const int tnn = (t + 2 < nodes) ? t + 2 : nodes - 1;
      const int2 ccNN = *(const int2*)(chb + 2 * tnn);
      __builtin_amdgcn_sched_barrier(0);

      // ---- D. B fragments + MFMA ----
      f16x8 bfrag[8];
#pragma unroll
      for (int kt = 0; kt < 8; ++kt)
        bfrag[kt] = *(const f16x8*)&hbuf[w][32 * kt + 8 * hi];
      f32x4 acc[5] = {};
#pragma unroll
      for (int kt = 0; kt < 8; ++kt) {
#pragma unroll
        for (int rt = 0; rt < 5; ++rt)
          acc[rt] = __builtin_amdgcn_mfma_f32_16x16x32_f16(
              afrag[rt][kt], bfrag[kt], acc[rt], 0, 0, 0);
      }

      // ---- E. gates + stores ----
      const float ce[8] = {cv0.x, cv0.y, cv0.z, cv0.w,
                           cv1.x, cv1.y, cv1.z, cv1.w};
      f32x4 hn4, cn4;
#pragma unroll
      for (int r = 0; r < 4; ++r) {
        const float zi = acc[0][r] + (float)xzi[r];
        const float zf0 = acc[1][r] + (float)xzf[2 * r];
        const float zf1 = acc[2][r] + (float)xzf[2 * r + 1];
        const float zo = acc[3][r] + (float)xzo[r];
        const float zg = acc[4][r] + (float)xzg[r];
        const float cn = ce[2 * r] * hsig(zf0) + ce[2 * r + 1] * hsig(zf1) +
                         hsig(zi) * tanh_fast(zg);
        cn4[r] = cn;
        hn4[r] = hsig(zo) * tanh_fast(cn);
      }
      if (col == 0) {
        *(f32x4*)(Hb + (size_t)t * U_ + u0) = hn4;
        *(f32x4*)(Cb + (size_t)t * U_ + u0) = cn4;
      }

      // ---- F. stage xz(t+1) into other LDS buffer ----
      if (tid < 160) *(f16x4*)&xzs[cbuf ^ 1][4 * tid] = xztmp;

      // ---- G. single barrier per step ----
      __syncthreads();

      hv = hv_n;
      cv0 = cv0n;
      cv1 = cv1n;
      ccT = ccN;
      ccN = ccNN;
      cbuf ^= 1;
    }
  }

  // zero rows t >= num_nodes
  const int total = (N_ - nodes) * U_;
  for (int idx = tid; idx < total; idx += 512)
    Hb[(size_t)nodes * U_ + idx] = 0.f;
}

extern "C" void kernel_launch(void* const* d_in, const int* in_sizes, int n_in,
                              void* d_out, int out_size, void* d_ws,
                              size_t ws_size, hipStream_t stream) {
  const float* state = (const float*)d_in[0];
  const float* tk    = (const float*)d_in[1];
  const float* Wk    = (const float*)d_in[2];
  const float* Wr    = (const float*)d_in[3];
  const float* bias  = (const float*)d_in[4];
  const int*   child = (const int*)d_in[5];
  const int*   nvp   = (const int*)d_in[6];
  float* H = (float*)d_out;

  const size_t c_bytes = (size_t)M_ * U_ * sizeof(float);      // 64 MiB
  float* C = (float*)d_ws;
  _Float16* XZ = (_Float16*)((char*)d_ws + c_bytes);

  x_gemm<<<M_ / 64, 256, 0, stream>>>(state, tk, H, C);
  xz_gemm<<<dim3(M_ / 64, 5), 256, 0, stream>>>(H, Wk, bias, nvp, XZ);
  tree_scan5<<<B_, 512, 0, stream>>>(Wr, child, nvp, XZ, H, C);
}

// Round 7
// 1044.559 us; speedup vs baseline: 1.0723x; 1.0090x over previous
//
#include <hip/hip_runtime.h>
#include <hip/hip_bf16.h>

#define B_ 128
#define N_ 1024
#define E_ 300
#define U_ 128
#define M_ (B_ * N_)   // 131072
#define Z_ (5 * U_)    // 640

typedef __attribute__((ext_vector_type(8))) short bf16x8;
typedef __attribute__((ext_vector_type(4))) float f32x4;
typedef _Float16 h2_t __attribute__((ext_vector_type(2)));
typedef _Float16 f16x4 __attribute__((ext_vector_type(4)));
typedef _Float16 f16x8 __attribute__((ext_vector_type(8)));

__device__ __forceinline__ short f2bf(float f) {
  unsigned u = __builtin_bit_cast(unsigned, f);
  u = (u + 0x7fffu + ((u >> 16) & 1u)) >> 16;
  return (short)u;
}

__device__ __forceinline__ float hsig(float z) {
  float v = __builtin_fmaf(z, 0.2f, 0.5f);
  v = v < 0.f ? 0.f : v;
  v = v > 1.f ? 1.f : v;
  return v;
}

__device__ __forceinline__ float tanh_fast(float x) {
  float p = __expf(2.f * x);
  return 1.f - 2.f * __builtin_amdgcn_rcpf(p + 1.f);
}

// ---------------- Kernel 1: x = relu(state @ Tk) -> H (d_out) and C (ws) ---
__global__ __launch_bounds__(256) void x_gemm(
    const float* __restrict__ A, const float* __restrict__ W,
    float* __restrict__ H, float* __restrict__ C) {
  __shared__ __align__(16) short As[64][40];
  __shared__ __align__(16) short Ws[128][40];
  const int tid = threadIdx.x;
  const int m0 = blockIdx.x * 64;
  f32x4 acc[8] = {};
  const int lane = tid & 63, wv = tid >> 6;
  const int lr = lane & 15, lg = lane >> 4;

  for (int kc = 0; kc < 10; ++kc) {
    const int k0 = kc * 32;
    {
      const int row = tid >> 2, kk = (tid & 3) * 8;
      const float* src = A + (size_t)(m0 + row) * E_ + k0 + kk;
      bf16x8 v;
      if (k0 + 32 <= E_) {
#pragma unroll
        for (int i = 0; i < 8; ++i) v[i] = f2bf(src[i]);
      } else {
#pragma unroll
        for (int i = 0; i < 8; ++i)
          v[i] = (k0 + kk + i < E_) ? f2bf(src[i]) : (short)0;
      }
      *(bf16x8*)&As[row][kk] = v;
    }
#pragma unroll
    for (int s = 0; s < 2; ++s) {
      const int slot = tid + s * 256;
      const int n = slot & 127, kg = slot >> 7;
      bf16x8 v;
      if (k0 + 32 <= E_) {
#pragma unroll
        for (int i = 0; i < 8; ++i) v[i] = f2bf(W[(k0 + kg * 8 + i) * U_ + n]);
      } else {
#pragma unroll
        for (int i = 0; i < 8; ++i) {
          const int k = k0 + kg * 8 + i;
          v[i] = (k < E_) ? f2bf(W[k * U_ + n]) : (short)0;
        }
      }
      *(bf16x8*)&Ws[n][kg * 8] = v;
    }
    __syncthreads();
    bf16x8 a = *(const bf16x8*)&As[wv * 16 + lr][lg * 8];
#pragma unroll
    for (int nt = 0; nt < 8; ++nt) {
      bf16x8 b = *(const bf16x8*)&Ws[nt * 16 + lr][lg * 8];
      acc[nt] = __builtin_amdgcn_mfma_f32_16x16x32_bf16(a, b, acc[nt], 0, 0, 0);
    }
    __syncthreads();
  }
#pragma unroll
  for (int nt = 0; nt < 8; ++nt) {
#pragma unroll
    for (int r = 0; r < 4; ++r) {
      const int m = m0 + wv * 16 + lg * 4 + r;
      const int n = nt * 16 + lr;
      float v = acc[nt][r];
      v = v > 0.f ? v : 0.f;
      H[(size_t)m * U_ + n] = v;
      C[(size_t)m * U_ + n] = v;
    }
  }
}

// ---------------- Kernel 2: xz = x @ K^T + bias (f16 out) ------------------
__global__ __launch_bounds__(256) void xz_gemm(
    const float* __restrict__ X, const float* __restrict__ K,
    const float* __restrict__ bias, const int* __restrict__ nv,
    _Float16* __restrict__ XZ) {
  const int m0 = blockIdx.x * 64;
  {
    const int bb = m0 >> 10;
    const int t0 = m0 & (N_ - 1);
    const int nodes = nv[2 * bb], leaves = nv[2 * bb + 1];
    if (t0 + 64 <= leaves || t0 >= nodes) return;
  }
  __shared__ __align__(16) short As[64][40];
  __shared__ __align__(16) short Ws[128][40];
  const int tid = threadIdx.x;
  const int n0 = blockIdx.y * 128;
  f32x4 acc[8] = {};
  const int lane = tid & 63, wv = tid >> 6;
  const int lr = lane & 15, lg = lane >> 4;

  for (int kc = 0; kc < 4; ++kc) {
    const int k0 = kc * 32;
    {
      const int row = tid >> 2, kk = (tid & 3) * 8;
      const float* src = X + (size_t)(m0 + row) * U_ + k0 + kk;
      bf16x8 v;
#pragma unroll
      for (int i = 0; i < 8; ++i) v[i] = f2bf(src[i]);
      *(bf16x8*)&As[row][kk] = v;
    }
#pragma unroll
    for (int s = 0; s < 2; ++s) {
      const int slot = tid + s * 256;
      const int n = slot >> 2, kk = (slot & 3) * 8;
      const float* src = K + (size_t)(n0 + n) * U_ + k0 + kk;
      bf16x8 v;
#pragma unroll
      for (int i = 0; i < 8; ++i) v[i] = f2bf(src[i]);
      *(bf16x8*)&Ws[n][kk] = v;
    }
    __syncthreads();
    bf16x8 a = *(const bf16x8*)&As[wv * 16 + lr][lg * 8];
#pragma unroll
    for (int nt = 0; nt < 8; ++nt) {
      bf16x8 b = *(const bf16x8*)&Ws[nt * 16 + lr][lg * 8];
      acc[nt] = __builtin_amdgcn_mfma_f32_16x16x32_bf16(a, b, acc[nt], 0, 0, 0);
    }
    __syncthreads();
  }
#pragma unroll
  for (int nt = 0; nt < 8; ++nt) {
    const int n = n0 + nt * 16 + lr;
    const float bv = bias[n];
#pragma unroll
    for (int r = 0; r < 4; ++r) {
      const int m = m0 + wv * 16 + lg * 4 + r;
      XZ[(size_t)m * Z_ + n] = (_Float16)(acc[nt][r] + bv);
    }
  }
}

// ---------------- Kernel 3: scan, NO vmcnt drain at the barrier ------------
// 512 threads = 8 waves; wave-local gates (validated R4 layout); cross-step
// gather pipelining (R6). NEW: rows t-1..t-3 are patched from an LDS ring,
// so global gathers only need rows <= t-4 (stores committed >=2 steps ago).
// The per-step barrier is then raw s_barrier + lgkmcnt(0) ONLY — global
// prefetches stay in flight across it (no vmcnt(0) drain, the R4-R6 stall).
__global__ __launch_bounds__(512, 2) void tree_scan6(
    const float* __restrict__ Wr,      // (640,256)
    const int*   __restrict__ child,   // (B,N,2)
    const int*   __restrict__ nv,      // (B,2)
    const _Float16* __restrict__ XZ,   // (B,N,640)
    float* __restrict__ H,             // (B,N,128)
    float* __restrict__ Cst) {         // (B,N,128)
  const int b = blockIdx.x;
  const int tid = threadIdx.x;
  const int lane = tid & 63, w = tid >> 6;
  const int col = lane & 15, hi = lane >> 4;
  int nodes = nv[2 * b];
  int leaves = nv[2 * b + 1];
  if (nodes > N_) nodes = N_;
  if (leaves < 0) leaves = 0;
  float* Hb = H + (size_t)b * N_ * U_;
  float* Cb = Cst + (size_t)b * N_ * U_;
  const int* chb = child + (size_t)b * N_ * 2;
  const _Float16* xzb = XZ + (size_t)b * N_ * Z_;

  // ---- preload R tiles as A-fragments: 5 rt x 8 kt x f16x8 ----
  f16x8 afrag[5][8];
  {
    const int rows[5] = {16 * w + col, 128 + 32 * w + 2 * col,
                         129 + 32 * w + 2 * col, 384 + 16 * w + col,
                         512 + 16 * w + col};
#pragma unroll
    for (int rt = 0; rt < 5; ++rt) {
      const float* rs = Wr + (size_t)rows[rt] * 256 + 8 * hi;
#pragma unroll
      for (int kt = 0; kt < 8; ++kt) {
#pragma unroll
        for (int i = 0; i < 8; ++i)
          afrag[rt][kt][i] = (_Float16)rs[32 * kt + i];
      }
    }
  }

  __shared__ __align__(16) _Float16 hbuf[8][256];  // wave-private h_ch (4KB)
  __shared__ __align__(16) float hring[4][128];    // last-3-rows h ring
  __shared__ __align__(16) float cring[4][128];    // last-3-rows c ring

  const int u0 = 16 * w + 4 * hi;   // gate base for this lane
  const int mc = 2 * u0;            // c_ch base index
  const int m4 = 4 * lane;          // h gather offset

  if (leaves < nodes) {
    // ---- prologue: synchronous loads for t = leaves ----
    int2 ccT = *(const int2*)(chb + 2 * leaves);
    float4 hv = *(const float4*)(Hb + (size_t)(lane < 32 ? ccT.x : ccT.y) * U_ +
                                 (m4 & 127));
    const float* cbp = Cb + (size_t)(w < 4 ? ccT.x : ccT.y) * U_ + (mc & 127);
    float4 cv0 = ((const float4*)cbp)[0];
    float4 cv1 = ((const float4*)cbp)[1];
    f16x4 xzi = *(const f16x4*)(xzb + (size_t)leaves * Z_ + u0);
    f16x8 xzf = *(const f16x8*)(xzb + (size_t)leaves * Z_ + 128 + mc);
    f16x4 xzo = *(const f16x4*)(xzb + (size_t)leaves * Z_ + 384 + u0);
    f16x4 xzg = *(const f16x4*)(xzb + (size_t)leaves * Z_ + 512 + u0);
    const int tn1 = (leaves + 1 < nodes) ? leaves + 1 : leaves;
    int2 ccN = *(const int2*)(chb + 2 * tn1);

    for (int t = leaves; t < nodes; ++t) {
      const int tn = (t + 1 < nodes) ? t + 1 : t;

      // ---- A. patch rows t-3..t-1 from the LDS ring (stale gathers) ----
      {
        const int ccl = (lane < 32) ? ccT.x : ccT.y;
        if (ccl >= leaves && ccl + 3 >= t)
          hv = *(const float4*)&hring[ccl & 3][m4 & 127];
        const int ccw = (w < 4) ? ccT.x : ccT.y;
        if (ccw >= leaves && ccw + 3 >= t) {
          cv0 = *(const float4*)&cring[ccw & 3][mc & 127];
          cv1 = *(const float4*)&cring[ccw & 3][(mc & 127) + 4];
        }
      }

      // ---- B. stage h -> wave-private LDS ----
      uint2 hp;
      hp.x = __builtin_bit_cast(unsigned, __builtin_amdgcn_cvt_pkrtz(hv.x, hv.y));
      hp.y = __builtin_bit_cast(unsigned, __builtin_amdgcn_cvt_pkrtz(hv.z, hv.w));
      *(uint2*)&hbuf[w][m4] = hp;
      __builtin_amdgcn_sched_barrier(0);

      // ---- C. issue gathers/prefetch for t+1 (kept AFTER B: vmcnt order) --
      float4 hv_n = *(const float4*)(
          Hb + (size_t)(lane < 32 ? ccN.x : ccN.y) * U_ + (m4 & 127));
      const float* cbn = Cb + (size_t)(w < 4 ? ccN.x : ccN.y) * U_ + (mc & 127);
      const float4 cv0n = ((const float4*)cbn)[0];
      const float4 cv1n = ((const float4*)cbn)[1];
      const f16x4 xzi_n = *(const f16x4*)(xzb + (size_t)tn * Z_ + u0);
      const f16x8 xzf_n = *(const f16x8*)(xzb + (size_t)tn * Z_ + 128 + mc);
      const f16x4 xzo_n = *(const f16x4*)(xzb + (size_t)tn * Z_ + 384 + u0);
      const f16x4 xzg_n = *(const f16x4*)(xzb + (size_t)tn * Z_ + 512 + u0);
      const int tnn = (t + 2 < nodes) ? t + 2 : nodes - 1;
      const int2 ccNN = *(const int2*)(chb + 2 * tnn);
      __builtin_amdgcn_sched_barrier(0);

      // ---- D. B fragments + MFMA ----
      f16x8 bfrag[8];
#pragma unroll
      for (int kt = 0; kt < 8; ++kt)
        bfrag[kt] = *(const f16x8*)&hbuf[w][32 * kt + 8 * hi];
      f32x4 acc[5] = {};
#pragma unroll
      for (int kt = 0; kt < 8; ++kt) {
#pragma unroll
        for (int rt = 0; rt < 5; ++rt)
          acc[rt] = __builtin_amdgcn_mfma_f32_16x16x32_f16(
              afrag[rt][kt], bfrag[kt], acc[rt], 0, 0, 0);
      }

      // ---- E. gates ----
      const float ce[8] = {cv0.x, cv0.y, cv0.z, cv0.w,
                           cv1.x, cv1.y, cv1.z, cv1.w};
      f32x4 hn4, cn4;
#pragma unroll
      for (int r = 0; r < 4; ++r) {
        const float zi = acc[0][r] + (float)xzi[r];
        const float zf0 = acc[1][r] + (float)xzf[2 * r];
        const float zf1 = acc[2][r] + (float)xzf[2 * r + 1];
        const float zo = acc[3][r] + (float)xzo[r];
        const float zg = acc[4][r] + (float)xzg[r];
        const float cn = ce[2 * r] * hsig(zf0) + ce[2 * r + 1] * hsig(zf1) +
                         hsig(zi) * tanh_fast(zg);
        cn4[r] = cn;
        hn4[r] = hsig(zo) * tanh_fast(cn);
      }

      // ---- F. stores: global (lazy) + LDS ring (for t+1..t+3 patches) ----
      if (col == 0) {
        *(f32x4*)(Hb + (size_t)t * U_ + u0) = hn4;
        *(f32x4*)(Cb + (size_t)t * U_ + u0) = cn4;
        *(f32x4*)&hring[t & 3][u0] = hn4;
        *(f32x4*)&cring[t & 3][u0] = cn4;
      }

      // ---- G. raw barrier: LDS visibility only, NO vmcnt drain ----
      asm volatile("s_waitcnt lgkmcnt(0)" ::: "memory");
      __builtin_amdgcn_sched_barrier(0);
      __builtin_amdgcn_s_barrier();
      __builtin_amdgcn_sched_barrier(0);

      hv = hv_n;
      cv0 = cv0n;
      cv1 = cv1n;
      xzi = xzi_n;
      xzf = xzf_n;
      xzo = xzo_n;
      xzg = xzg_n;
      ccT = ccN;
      ccN = ccNN;
    }
  }

  // zero rows t >= num_nodes
  const int total = (N_ - nodes) * U_;
  for (int idx = tid; idx < total; idx += 512)
    Hb[(size_t)nodes * U_ + idx] = 0.f;
}

extern "C" void kernel_launch(void* const* d_in, const int* in_sizes, int n_in,
                              void* d_out, int out_size, void* d_ws,
                              size_t ws_size, hipStream_t stream) {
  const float* state = (const float*)d_in[0];
  const float* tk    = (const float*)d_in[1];
  const float* Wk    = (const float*)d_in[2];
  const float* Wr    = (const float*)d_in[3];
  const float* bias  = (const float*)d_in[4];
  const int*   child = (const int*)d_in[5];
  const int*   nvp   = (const int*)d_in[6];
  float* H = (float*)d_out;

  const size_t c_bytes = (size_t)M_ * U_ * sizeof(float);      // 64 MiB
  float* C = (float*)d_ws;
  _Float16* XZ = (_Float16*)((char*)d_ws + c_bytes);

  x_gemm<<<M_ / 64, 256, 0, stream>>>(state, tk, H, C);
  xz_gemm<<<dim3(M_ / 64, 5), 256, 0, stream>>>(H, Wk, bias, nvp, XZ);
  tree_scan6<<<B_, 512, 0, stream>>>(Wr, child, nvp, XZ, H, C);
}

// Round 8
// 413.339 us; speedup vs baseline: 2.7097x; 2.5271x over previous
//
#include <hip/hip_runtime.h>
#include <hip/hip_bf16.h>

#define B_ 128
#define N_ 1024
#define E_ 300
#define U_ 128
#define M_ (B_ * N_)   // 131072
#define Z_ (5 * U_)    // 640
#define LMAXT 40       // level buckets (last bucket = sequential, t-ordered)
#define LPAR 14        // levels 1..LPAR-1 run as parallel GEMMs; rest in tail

typedef __attribute__((ext_vector_type(8))) short bf16x8;
typedef __attribute__((ext_vector_type(4))) float f32x4;
typedef _Float16 h2_t __attribute__((ext_vector_type(2)));
typedef _Float16 f16x4 __attribute__((ext_vector_type(4)));
typedef _Float16 f16x8 __attribute__((ext_vector_type(8)));

__device__ __forceinline__ short f2bf(float f) {
  unsigned u = __builtin_bit_cast(unsigned, f);
  u = (u + 0x7fffu + ((u >> 16) & 1u)) >> 16;
  return (short)u;
}

__device__ __forceinline__ float hsig(float z) {
  float v = __builtin_fmaf(z, 0.2f, 0.5f);
  v = v < 0.f ? 0.f : v;
  v = v > 1.f ? 1.f : v;
  return v;
}

__device__ __forceinline__ float tanh_fast(float x) {
  float p = __expf(2.f * x);
  return 1.f - 2.f * __builtin_amdgcn_rcpf(p + 1.f);
}

__device__ __forceinline__ unsigned pk2(float a, float b) {
  return __builtin_bit_cast(unsigned, __builtin_amdgcn_cvt_pkrtz(a, b));
}

// ---------------- Kernel 1: x = relu(state @ Tk) -> H (d_out) and C (ws) ---
__global__ __launch_bounds__(256) void x_gemm(
    const float* __restrict__ A, const float* __restrict__ W,
    float* __restrict__ H, float* __restrict__ C) {
  __shared__ __align__(16) short As[64][40];
  __shared__ __align__(16) short Ws[128][40];
  const int tid = threadIdx.x;
  const int m0 = blockIdx.x * 64;
  f32x4 acc[8] = {};
  const int lane = tid & 63, wv = tid >> 6;
  const int lr = lane & 15, lg = lane >> 4;

  for (int kc = 0; kc < 10; ++kc) {
    const int k0 = kc * 32;
    {
      const int row = tid >> 2, kk = (tid & 3) * 8;
      const float* src = A + (size_t)(m0 + row) * E_ + k0 + kk;
      bf16x8 v;
      if (k0 + 32 <= E_) {
#pragma unroll
        for (int i = 0; i < 8; ++i) v[i] = f2bf(src[i]);
      } else {
#pragma unroll
        for (int i = 0; i < 8; ++i)
          v[i] = (k0 + kk + i < E_) ? f2bf(src[i]) : (short)0;
      }
      *(bf16x8*)&As[row][kk] = v;
    }
#pragma unroll
    for (int s = 0; s < 2; ++s) {
      const int slot = tid + s * 256;
      const int n = slot & 127, kg = slot >> 7;
      bf16x8 v;
      if (k0 + 32 <= E_) {
#pragma unroll
        for (int i = 0; i < 8; ++i) v[i] = f2bf(W[(k0 + kg * 8 + i) * U_ + n]);
      } else {
#pragma unroll
        for (int i = 0; i < 8; ++i) {
          const int k = k0 + kg * 8 + i;
          v[i] = (k < E_) ? f2bf(W[k * U_ + n]) : (short)0;
        }
      }
      *(bf16x8*)&Ws[n][kg * 8] = v;
    }
    __syncthreads();
    bf16x8 a = *(const bf16x8*)&As[wv * 16 + lr][lg * 8];
#pragma unroll
    for (int nt = 0; nt < 8; ++nt) {
      bf16x8 b = *(const bf16x8*)&Ws[nt * 16 + lr][lg * 8];
      acc[nt] = __builtin_amdgcn_mfma_f32_16x16x32_bf16(a, b, acc[nt], 0, 0, 0);
    }
    __syncthreads();
  }
#pragma unroll
  for (int nt = 0; nt < 8; ++nt) {
#pragma unroll
    for (int r = 0; r < 4; ++r) {
      const int m = m0 + wv * 16 + lg * 4 + r;
      const int n = nt * 16 + lr;
      float v = acc[nt][r];
      v = v > 0.f ? v : 0.f;
      H[(size_t)m * U_ + n] = v;
      C[(size_t)m * U_ + n] = v;
    }
  }
}

// ---------------- Kernel 2: xz = x @ K^T + bias (f16 out), active rows -----
__global__ __launch_bounds__(256) void xz_gemm(
    const float* __restrict__ X, const float* __restrict__ K,
    const float* __restrict__ bias, const int* __restrict__ nv,
    _Float16* __restrict__ XZ) {
  const int m0 = blockIdx.x * 64;
  {
    const int bb = m0 >> 10;
    const int t0 = m0 & (N_ - 1);
    const int nodes = nv[2 * bb], leaves = nv[2 * bb + 1];
    if (t0 + 64 <= leaves || t0 >= nodes) return;
  }
  __shared__ __align__(16) short As[64][40];
  __shared__ __align__(16) short Ws[128][40];
  const int tid = threadIdx.x;
  const int n0 = blockIdx.y * 128;
  f32x4 acc[8] = {};
  const int lane = tid & 63, wv = tid >> 6;
  const int lr = lane & 15, lg = lane >> 4;

  for (int kc = 0; kc < 4; ++kc) {
    const int k0 = kc * 32;
    {
      const int row = tid >> 2, kk = (tid & 3) * 8;
      const float* src = X + (size_t)(m0 + row) * U_ + k0 + kk;
      bf16x8 v;
#pragma unroll
      for (int i = 0; i < 8; ++i) v[i] = f2bf(src[i]);
      *(bf16x8*)&As[row][kk] = v;
    }
#pragma unroll
    for (int s = 0; s < 2; ++s) {
      const int slot = tid + s * 256;
      const int n = slot >> 2, kk = (slot & 3) * 8;
      const float* src = K + (size_t)(n0 + n) * U_ + k0 + kk;
      bf16x8 v;
#pragma unroll
      for (int i = 0; i < 8; ++i) v[i] = f2bf(src[i]);
      *(bf16x8*)&Ws[n][kk] = v;
    }
    __syncthreads();
    bf16x8 a = *(const bf16x8*)&As[wv * 16 + lr][lg * 8];
#pragma unroll
    for (int nt = 0; nt < 8; ++nt) {
      bf16x8 b = *(const bf16x8*)&Ws[nt * 16 + lr][lg * 8];
      acc[nt] = __builtin_amdgcn_mfma_f32_16x16x32_bf16(a, b, acc[nt], 0, 0, 0);
    }
    __syncthreads();
  }
#pragma unroll
  for (int nt = 0; nt < 8; ++nt) {
    const int n = n0 + nt * 16 + lr;
    const float bv = bias[n];
#pragma unroll
    for (int r = 0; r < 4; ++r) {
      const int m = m0 + wv * 16 + lg * 4 + r;
      XZ[(size_t)m * Z_ + n] = (_Float16)(acc[nt][r] + bv);
    }
  }
}

// ---------------- Kernel W: Wr f32 -> f16 (shared by level/tail kernels) ---
__global__ __launch_bounds__(256) void wcvt(const float* __restrict__ Wr,
                                            _Float16* __restrict__ W16) {
  const int i = (blockIdx.x * 256 + threadIdx.x) * 2;
  if (i < 640 * 256) {
    W16[i] = (_Float16)Wr[i];
    W16[i + 1] = (_Float16)Wr[i + 1];
  }
}

// ---------------- Kernel C1: per-batch levelize (parallel fixpoint) --------
__global__ __launch_bounds__(512) void levelize(
    const int* __restrict__ child, const int* __restrict__ nv,
    int* __restrict__ lv, int* __restrict__ rank, int* __restrict__ cnt) {
  const int b = blockIdx.x;
  const int tid = threadIdx.x;
  int nodes = nv[2 * b];
  int leaves = nv[2 * b + 1];
  if (nodes > N_) nodes = N_;
  if (leaves < 0) leaves = 0;

  __shared__ short lvs[N_];
  __shared__ int chs[2 * N_];
  __shared__ int cnts[LMAXT];
  __shared__ int changed;

  for (int i = tid; i < N_; i += 512) lvs[i] = 0;
  for (int i = tid; i < 2 * N_; i += 512) chs[i] = child[(size_t)b * 2 * N_ + i];
  if (tid < LMAXT) cnts[tid] = 0;
  __syncthreads();

  // fixpoint sweeps: lv(t) = 1 + max(lv(c0), lv(c1)); child>=t reads pre-
  // update state (= level 0 data), matching the reference's take-then-update.
  int stable = 0;
  for (int s = 0; s < 64; ++s) {
    if (tid == 0) changed = 0;
    __syncthreads();
    int any = 0;
    for (int t = leaves + tid; t < nodes; t += 512) {
      const int c0 = chs[2 * t], c1 = chs[2 * t + 1];
      const int l0 = (c0 < t && c0 >= 0) ? lvs[c0] : 0;
      const int l1 = (c1 < t && c1 >= 0) ? lvs[c1] : 0;
      const int l = 1 + (l0 > l1 ? l0 : l1);
      if (l > (int)lvs[t]) { lvs[t] = (short)l; any = 1; }
    }
    if (any) changed = 1;
    __syncthreads();
    if (!changed) { stable = 1; break; }
  }
  if (!stable) {  // pathological depth: exact serial pass (t-order is valid)
    if (tid == 0) {
      for (int t = leaves; t < nodes; ++t) {
        const int c0 = chs[2 * t], c1 = chs[2 * t + 1];
        const int l0 = (c0 < t && c0 >= 0) ? lvs[c0] : 0;
        const int l1 = (c1 < t && c1 >= 0) ? lvs[c1] : 0;
        lvs[t] = (short)(1 + (l0 > l1 ? l0 : l1));
      }
    }
    __syncthreads();
  }

  // ranks: atomic for buckets < LMAXT-1 (order-free), t-ordered for last.
  for (int t = leaves + tid; t < nodes; t += 512) {
    int l = lvs[t];
    if (l > LMAXT - 1) l = LMAXT - 1;
    lv[b * N_ + t] = l;
    if (l < LMAXT - 1) rank[b * N_ + t] = atomicAdd(&cnts[l], 1);
  }
  __syncthreads();
  if (tid == 0) {
    for (int t = leaves; t < nodes; ++t)
      if ((int)lvs[t] >= LMAXT - 1) rank[b * N_ + t] = cnts[LMAXT - 1]++;
  }
  __syncthreads();
  if (tid < LMAXT) cnt[tid * 128 + b] = cnts[tid];
}

// ---------------- Kernel C2: global offsets --------------------------------
__global__ __launch_bounds__(64) void offsets(
    const int* __restrict__ cnt, int* __restrict__ pos, int* __restrict__ goff) {
  const int l = threadIdx.x;
  __shared__ int tot[LMAXT];
  if (l < LMAXT) {
    int s = 0;
    for (int b = 0; b < 128; ++b) {
      pos[l * 128 + b] = s;
      s += cnt[l * 128 + b];
    }
    tot[l] = s;
  }
  __syncthreads();
  if (l == 0) {
    int g = 0;
    for (int i = 0; i < LMAXT; ++i) { goff[i] = g; g += tot[i]; }
    goff[LMAXT] = g;
  }
  __syncthreads();
  if (l < LMAXT) {
    const int g = goff[l];
    for (int b = 0; b < 128; ++b) pos[l * 128 + b] += g;
  }
}

// ---------------- Kernel C3: scatter node list + zero invalid rows ---------
__global__ __launch_bounds__(256) void scatter_zero(
    const int* __restrict__ nv, const int* __restrict__ lv,
    const int* __restrict__ rank, const int* __restrict__ pos,
    int* __restrict__ glist, float* __restrict__ H) {
  const int b = blockIdx.x;
  const int tid = threadIdx.x;
  int nodes = nv[2 * b];
  int leaves = nv[2 * b + 1];
  if (nodes > N_) nodes = N_;
  if (leaves < 0) leaves = 0;
  for (int t = leaves + tid; t < nodes; t += 256) {
    const int l = lv[b * N_ + t];
    glist[pos[l * 128 + b] + rank[b * N_ + t]] = (b << 10) | t;
  }
  const int total = (N_ - nodes) * U_;
  for (int idx = tid; idx < total; idx += 256)
    H[(size_t)b * N_ * U_ + nodes * U_ + idx] = 0.f;
}

// ---------------- Kernel L: one level as a real MFMA GEMM ------------------
// 512 thr = 8 waves; 16 nodes per tile (B cols = 16 DISTINCT nodes — no
// broadcast waste). Wave w owns z-rows {16w+j, 128+32w+2j, 129+32w+2j,
// 384+16w+j, 512+16w+j} (HW-validated mapping); lane (col,hi) gets all 5 z's
// for node col, units 16w+4hi+r. acc is initialized from XZ (no epilogue add).
__global__ __launch_bounds__(512, 2) void level_gemm(
    int lvl, const _Float16* __restrict__ W16, const int* __restrict__ child,
    const int* __restrict__ goff, const int* __restrict__ glist,
    const _Float16* __restrict__ XZ, float* __restrict__ H,
    float* __restrict__ C) {
  const int base = goff[lvl];
  const int count = goff[lvl + 1] - base;
  if (count <= 0) return;
  const int tid = threadIdx.x;
  const int lane = tid & 63, w = tid >> 6;
  const int col = lane & 15, hi = lane >> 4;
  const int u0 = 16 * w + 4 * hi;
  const int mc = 2 * u0;

  // weights resident across all chunks of this block
  f16x8 afrag[5][8];
  {
    const int rows[5] = {16 * w + col, 128 + 32 * w + 2 * col,
                         129 + 32 * w + 2 * col, 384 + 16 * w + col,
                         512 + 16 * w + col};
#pragma unroll
    for (int rt = 0; rt < 5; ++rt) {
      const _Float16* rs = W16 + (size_t)rows[rt] * 256 + 8 * hi;
#pragma unroll
      for (int kt = 0; kt < 8; ++kt) afrag[rt][kt] = *(const f16x8*)(rs + 32 * kt);
    }
  }

  __shared__ __align__(16) _Float16 hbuf[16][272];  // 544B stride: even banks

  const int nchunk = (count + 15) >> 4;
  for (int chunk = blockIdx.x; chunk < nchunk; chunk += gridDim.x) {
    const int cb = base + chunk * 16;
    int rem = count - chunk * 16;
    if (rem > 16) rem = 16;

    // ---- staging loads FIRST (consumed first): h_ch of node j=tid>>5 ----
    const int j = tid >> 5, s = tid & 31;
    const int nidj = glist[cb + (j < rem ? j : rem - 1)];
    const int bj = nidj >> 10, tj = nidj & 1023;
    const int chj = child[((size_t)bj << 11) + 2 * tj + (s >> 4)];
    const float* hsrc =
        H + (((size_t)(bj << 10) + chj) << 7) + ((s & 15) << 3);
    const float4 a0 = *(const float4*)hsrc;
    const float4 a1 = *(const float4*)(hsrc + 4);

    // ---- per-lane node (col): xz + c_ch gathers (consumed after MFMA) ----
    const int nidc = glist[cb + (col < rem ? col : rem - 1)];
    const int bc = nidc >> 10, tc = nidc & 1023;
    const _Float16* xzr = XZ + ((size_t)((bc << 10) | tc)) * Z_;
    const f16x4 xzi = *(const f16x4*)(xzr + u0);
    const f16x8 xzf = *(const f16x8*)(xzr + 128 + mc);
    const f16x4 xzo = *(const f16x4*)(xzr + 384 + u0);
    const f16x4 xzg = *(const f16x4*)(xzr + 512 + u0);
    const int csel = child[((size_t)bc << 11) + 2 * tc + (mc >> 7)];
    const float* cbp = C + (((size_t)(bc << 10) + csel) << 7) + (mc & 127);
    const float4 cv0 = ((const float4*)cbp)[0];
    const float4 cv1 = ((const float4*)cbp)[1];

    // ---- stage h -> LDS ----
    uint4 hp;
    hp.x = pk2(a0.x, a0.y);
    hp.y = pk2(a0.z, a0.w);
    hp.z = pk2(a1.x, a1.y);
    hp.w = pk2(a1.z, a1.w);
    *(uint4*)&hbuf[j][(s >> 4) * 128 + (s & 15) * 8] = hp;
    __syncthreads();

    // ---- acc init from xz, then MFMA over K=256 ----
    f32x4 acc[5];
#pragma unroll
    for (int r = 0; r < 4; ++r) {
      acc[0][r] = (float)xzi[r];
      acc[1][r] = (float)xzf[2 * r];
      acc[2][r] = (float)xzf[2 * r + 1];
      acc[3][r] = (float)xzo[r];
      acc[4][r] = (float)xzg[r];
    }
#pragma unroll
    for (int kt = 0; kt < 8; ++kt) {
      const f16x8 bf = *(const f16x8*)&hbuf[col][32 * kt + 8 * hi];
#pragma unroll
      for (int rt = 0; rt < 5; ++rt)
        acc[rt] = __builtin_amdgcn_mfma_f32_16x16x32_f16(afrag[rt][kt], bf,
                                                         acc[rt], 0, 0, 0);
    }

    // ---- gates + stores (node col, units u0..u0+3) ----
    const float ce[8] = {cv0.x, cv0.y, cv0.z, cv0.w,
                         cv1.x, cv1.y, cv1.z, cv1.w};
    f32x4 hn4, cn4;
#pragma unroll
    for (int r = 0; r < 4; ++r) {
      const float cn = ce[2 * r] * hsig(acc[1][r]) +
                       ce[2 * r + 1] * hsig(acc[2][r]) +
                       hsig(acc[0][r]) * tanh_fast(acc[4][r]);
      cn4[r] = cn;
      hn4[r] = hsig(acc[3][r]) * tanh_fast(cn);
    }
    if (col < rem) {
      const size_t rowb = ((size_t)((bc << 10) | tc)) << 7;
      *(f32x4*)(H + rowb + u0) = hn4;
      *(f32x4*)(C + rowb + u0) = cn4;
    }
    __syncthreads();  // hbuf reuse next chunk
  }
}

// ---------------- Kernel T: sequential tail for levels >= LPAR -------------
__global__ __launch_bounds__(512, 2) void tail_scan(
    const _Float16* __restrict__ W16, const int* __restrict__ child,
    const int* __restrict__ nv, const int* __restrict__ pos,
    const int* __restrict__ cnt, const int* __restrict__ glist,
    const _Float16* __restrict__ XZ, float* __restrict__ H,
    float* __restrict__ C) {
  const int b = blockIdx.x;
  const int tid = threadIdx.x;
  const int lane = tid & 63, w = tid >> 6;
  const int col = lane & 15, hi = lane >> 4;
  const int u0 = 16 * w + 4 * hi;
  const int mc = 2 * u0;
  const int m4 = 4 * lane;

  f16x8 afrag[5][8];
  {
    const int rows[5] = {16 * w + col, 128 + 32 * w + 2 * col,
                         129 + 32 * w + 2 * col, 384 + 16 * w + col,
                         512 + 16 * w + col};
#pragma unroll
    for (int rt = 0; rt < 5; ++rt) {
      const _Float16* rs = W16 + (size_t)rows[rt] * 256 + 8 * hi;
#pragma unroll
      for (int kt = 0; kt < 8; ++kt) afrag[rt][kt] = *(const f16x8*)(rs + 32 * kt);
    }
  }

  __shared__ __align__(16) _Float16 hb1[256];
  const int* chb = child + (size_t)b * 2 * N_;
  float* Hb = H + (size_t)b * N_ * U_;
  float* Cb = C + (size_t)b * N_ * U_;
  const _Float16* xzb = XZ + (size_t)b * N_ * Z_;

  for (int l = LPAR; l < LMAXT; ++l) {
    const int p0 = pos[l * 128 + b];
    const int n = cnt[l * 128 + b];
    for (int i = 0; i < n; ++i) {
      const int t = glist[p0 + i] & 1023;
      if (tid < 64) {
        const int ch = chb[2 * t + (m4 >> 7)];
        const float4 hv = *(const float4*)(Hb + ((size_t)ch << 7) + (m4 & 127));
        uint2 hp;
        hp.x = pk2(hv.x, hv.y);
        hp.y = pk2(hv.z, hv.w);
        *(uint2*)&hb1[m4] = hp;
      }
      const int cs = chb[2 * t + (mc >> 7)];
      const float* cbp = Cb + ((size_t)cs << 7) + (mc & 127);
      const float4 cv0 = ((const float4*)cbp)[0];
      const float4 cv1 = ((const float4*)cbp)[1];
      const _Float16* xzr = xzb + (size_t)t * Z_;
      const f16x4 xzi = *(const f16x4*)(xzr + u0);
      const f16x8 xzf = *(const f16x8*)(xzr + 128 + mc);
      const f16x4 xzo = *(const f16x4*)(xzr + 384 + u0);
      const f16x4 xzg = *(const f16x4*)(xzr + 512 + u0);
      __syncthreads();
      f32x4 acc[5];
#pragma unroll
      for (int r = 0; r < 4; ++r) {
        acc[0][r] = (float)xzi[r];
        acc[1][r] = (float)xzf[2 * r];
        acc[2][r] = (float)xzf[2 * r + 1];
        acc[3][r] = (float)xzo[r];
        acc[4][r] = (float)xzg[r];
      }
#pragma unroll
      for (int kt = 0; kt < 8; ++kt) {
        const f16x8 bf = *(const f16x8*)&hb1[32 * kt + 8 * hi];
#pragma unroll
        for (int rt = 0; rt < 5; ++rt)
          acc[rt] = __builtin_amdgcn_mfma_f32_16x16x32_f16(afrag[rt][kt], bf,
                                                           acc[rt], 0, 0, 0);
      }
      const float ce[8] = {cv0.x, cv0.y, cv0.z, cv0.w,
                           cv1.x, cv1.y, cv1.z, cv1.w};
      f32x4 hn4, cn4;
#pragma unroll
      for (int r = 0; r < 4; ++r) {
        const float cn = ce[2 * r] * hsig(acc[1][r]) +
                         ce[2 * r + 1] * hsig(acc[2][r]) +
                         hsig(acc[0][r]) * tanh_fast(acc[4][r]);
        cn4[r] = cn;
        hn4[r] = hsig(acc[3][r]) * tanh_fast(cn);
      }
      if (col == 0) {
        *(f32x4*)(Hb + ((size_t)t << 7) + u0) = hn4;
        *(f32x4*)(Cb + ((size_t)t << 7) + u0) = cn4;
      }
      __syncthreads();
    }
  }
}

// ---------------- Fallback (R7 path): tree_scan6 ---------------------------
__global__ __launch_bounds__(512, 2) void tree_scan6(
    const float* __restrict__ Wr, const int* __restrict__ child,
    const int* __restrict__ nv, const _Float16* __restrict__ XZ,
    float* __restrict__ H, float* __restrict__ Cst) {
  const int b = blockIdx.x;
  const int tid = threadIdx.x;
  const int lane = tid & 63, w = tid >> 6;
  const int col = lane & 15, hi = lane >> 4;
  int nodes = nv[2 * b];
  int leaves = nv[2 * b + 1];
  if (nodes > N_) nodes = N_;
  if (leaves < 0) leaves = 0;
  float* Hb = H + (size_t)b * N_ * U_;
  float* Cb = Cst + (size_t)b * N_ * U_;
  const int* chb = child + (size_t)b * N_ * 2;
  const _Float16* xzb = XZ + (size_t)b * N_ * Z_;

  f16x8 afrag[5][8];
  {
    const int rows[5] = {16 * w + col, 128 + 32 * w + 2 * col,
                         129 + 32 * w + 2 * col, 384 + 16 * w + col,
                         512 + 16 * w + col};
#pragma unroll
    for (int rt = 0; rt < 5; ++rt) {
      const float* rs = Wr + (size_t)rows[rt] * 256 + 8 * hi;
#pragma unroll
      for (int kt = 0; kt < 8; ++kt) {
#pragma unroll
        for (int i = 0; i < 8; ++i)
          afrag[rt][kt][i] = (_Float16)rs[32 * kt + i];
      }
    }
  }

  __shared__ __align__(16) _Float16 hbuf[8][256];
  const int u0 = 16 * w + 4 * hi;
  const int mc = 2 * u0;
  const int m4 = 4 * lane;

  if (leaves < nodes) {
    int2 ccT = *(const int2*)(chb + 2 * leaves);
    float4 hv = *(const float4*)(Hb + (size_t)(lane < 32 ? ccT.x : ccT.y) * U_ +
                                 (m4 & 127));
    const float* cbp = Cb + (size_t)(w < 4 ? ccT.x : ccT.y) * U_ + (mc & 127);
    float4 cv0 = ((const float4*)cbp)[0];
    float4 cv1 = ((const float4*)cbp)[1];
    f16x4 xzi = *(const f16x4*)(xzb + (size_t)leaves * Z_ + u0);
    f16x8 xzf = *(const f16x8*)(xzb + (size_t)leaves * Z_ + 128 + mc);
    f16x4 xzo = *(const f16x4*)(xzb + (size_t)leaves * Z_ + 384 + u0);
    f16x4 xzg = *(const f16x4*)(xzb + (size_t)leaves * Z_ + 512 + u0);
    const int tn1 = (leaves + 1 < nodes) ? leaves + 1 : leaves;
    int2 ccN = *(const int2*)(chb + 2 * tn1);

    for (int t = leaves; t < nodes; ++t) {
      const int tn = (t + 1 < nodes) ? t + 1 : t;
      if (t > leaves) {
        if (ccT.x == t - 1 && lane < 32)
          hv = *(const float4*)(Hb + (size_t)(t - 1) * U_ + m4);
        if (ccT.y == t - 1 && lane >= 32)
          hv = *(const float4*)(Hb + (size_t)(t - 1) * U_ + (m4 & 127));
        const int crow = (w < 4) ? ccT.x : ccT.y;
        if (crow == t - 1) {
          const float* cpp = Cb + (size_t)(t - 1) * U_ + (mc & 127);
          cv0 = ((const float4*)cpp)[0];
          cv1 = ((const float4*)cpp)[1];
        }
      }
      uint2 hp;
      hp.x = pk2(hv.x, hv.y);
      hp.y = pk2(hv.z, hv.w);
      *(uint2*)&hbuf[w][m4] = hp;
      __builtin_amdgcn_sched_barrier(0);
      float4 hv_n = *(const float4*)(
          Hb + (size_t)(lane < 32 ? ccN.x : ccN.y) * U_ + (m4 & 127));
      const float* cbn = Cb + (size_t)(w < 4 ? ccN.x : ccN.y) * U_ + (mc & 127);
      const float4 cv0n = ((const float4*)cbn)[0];
      const float4 cv1n = ((const float4*)cbn)[1];
      const f16x4 xzi_n = *(const f16x4*)(xzb + (size_t)tn * Z_ + u0);
      const f16x8 xzf_n = *(const f16x8*)(xzb + (size_t)tn * Z_ + 128 + mc);
      const f16x4 xzo_n = *(const f16x4*)(xzb + (size_t)tn * Z_ + 384 + u0);
      const f16x4 xzg_n = *(const f16x4*)(xzb + (size_t)tn * Z_ + 512 + u0);
      const int tnn = (t + 2 < nodes) ? t + 2 : nodes - 1;
      const int2 ccNN = *(const int2*)(chb + 2 * tnn);
      __builtin_amdgcn_sched_barrier(0);
      f16x8 bfrag[8];
#pragma unroll
      for (int kt = 0; kt < 8; ++kt)
        bfrag[kt] = *(const f16x8*)&hbuf[w][32 * kt + 8 * hi];
      f32x4 acc[5] = {};
#pragma unroll
      for (int kt = 0; kt < 8; ++kt) {
#pragma unroll
        for (int rt = 0; rt < 5; ++rt)
          acc[rt] = __builtin_amdgcn_mfma_f32_16x16x32_f16(
              afrag[rt][kt], bfrag[kt], acc[rt], 0, 0, 0);
      }
      const float ce[8] = {cv0.x, cv0.y, cv0.z, cv0.w,
                           cv1.x, cv1.y, cv1.z, cv1.w};
      f32x4 hn4, cn4;
#pragma unroll
      for (int r = 0; r < 4; ++r) {
        const float zi = acc[0][r] + (float)xzi[r];
        const float zf0 = acc[1][r] + (float)xzf[2 * r];
        const float zf1 = acc[2][r] + (float)xzf[2 * r + 1];
        const float zo = acc[3][r] + (float)xzo[r];
        const float zg = acc[4][r] + (float)xzg[r];
        const float cn = ce[2 * r] * hsig(zf0) + ce[2 * r + 1] * hsig(zf1) +
                         hsig(zi) * tanh_fast(zg);
        cn4[r] = cn;
        hn4[r] = hsig(zo) * tanh_fast(cn);
      }
      if (col == 0) {
        *(f32x4*)(Hb + (size_t)t * U_ + u0) = hn4;
        *(f32x4*)(Cb + (size_t)t * U_ + u0) = cn4;
      }
      asm volatile("s_waitcnt lgkmcnt(0)" ::: "memory");
      __builtin_amdgcn_sched_barrier(0);
      __builtin_amdgcn_s_barrier();
      __builtin_amdgcn_sched_barrier(0);
      hv = hv_n; cv0 = cv0n; cv1 = cv1n;
      xzi = xzi_n; xzf = xzf_n; xzo = xzo_n; xzg = xzg_n;
      ccT = ccN; ccN = ccNN;
    }
  }
  const int total = (N_ - nodes) * U_;
  for (int idx = tid; idx < total; idx += 512)
    Hb[(size_t)nodes * U_ + idx] = 0.f;
}

extern "C" void kernel_launch(void* const* d_in, const int* in_sizes, int n_in,
                              void* d_out, int out_size, void* d_ws,
                              size_t ws_size, hipStream_t stream) {
  const float* state = (const float*)d_in[0];
  const float* tk    = (const float*)d_in[1];
  const float* Wk    = (const float*)d_in[2];
  const float* Wr    = (const float*)d_in[3];
  const float* bias  = (const float*)d_in[4];
  const int*   child = (const int*)d_in[5];
  const int*   nvp   = (const int*)d_in[6];
  float* H = (float*)d_out;

  const size_t MB = 1024ull * 1024ull;
  const size_t meta_sz = 2 * MB;
  const size_t c_bytes = (size_t)M_ * U_ * sizeof(float);      // 64 MiB
  const size_t xz_bytes = (size_t)M_ * Z_ * sizeof(_Float16);  // 160 MiB

  if (ws_size >= meta_sz + c_bytes + xz_bytes) {
    char* wsb = (char*)d_ws;
    _Float16* W16 = (_Float16*)(wsb + 0x0);
    int* lv    = (int*)(wsb + 0x50000);
    int* rank  = (int*)(wsb + 0xD0000);
    int* cnt   = (int*)(wsb + 0x150000);
    int* pos   = (int*)(wsb + 0x158000);
    int* goff  = (int*)(wsb + 0x160000);
    int* glist = (int*)(wsb + 0x161000);
    float* C = (float*)(wsb + meta_sz);
    _Float16* XZ = (_Float16*)(wsb + meta_sz + c_bytes);

    x_gemm<<<M_ / 64, 256, 0, stream>>>(state, tk, H, C);
    wcvt<<<320, 256, 0, stream>>>(Wr, W16);
    xz_gemm<<<dim3(M_ / 64, 5), 256, 0, stream>>>(H, Wk, bias, nvp, XZ);
    levelize<<<B_, 512, 0, stream>>>(child, nvp, lv, rank, cnt);
    offsets<<<1, 64, 0, stream>>>(cnt, pos, goff);
    scatter_zero<<<B_, 256, 0, stream>>>(nvp, lv, rank, pos, glist, H);
    static const int lg[LPAR] = {0, 512, 512, 256, 256, 128, 128,
                                 64, 64, 64, 32, 32, 32, 32};
    for (int l = 1; l < LPAR; ++l)
      level_gemm<<<lg[l], 512, 0, stream>>>(l, W16, child, goff, glist, XZ, H,
                                            C);
    tail_scan<<<B_, 512, 0, stream>>>(W16, child, nvp, pos, cnt, glist, XZ, H,
                                      C);
  } else {
    float* C = (float*)d_ws;
    _Float16* XZ = (_Float16*)((char*)d_ws + c_bytes);
    x_gemm<<<M_ / 64, 256, 0, stream>>>(state, tk, H, C);
    xz_gemm<<<dim3(M_ / 64, 5), 256, 0, stream>>>(H, Wk, bias, nvp, XZ);
    tree_scan6<<<B_, 512, 0, stream>>>(Wr, child, nvp, XZ, H, C);
  }
}